// Round 3
// baseline (312.582 us; speedup 1.0000x reference)
//
#include <hip/hip_runtime.h>

#define B_ 4
#define C_ 256
#define N_ 4096
#define LOG2E 1.4426950408889634f

typedef short short8 __attribute__((ext_vector_type(8)));
typedef float float4v __attribute__((ext_vector_type(4)));
typedef unsigned int uint2v __attribute__((ext_vector_type(2)));

__device__ inline unsigned short f2b(float x){
  unsigned u = __builtin_bit_cast(unsigned, x);
  u = u + 0x7FFFu + ((u >> 16) & 1u);
  return (unsigned short)(u >> 16);
}

// ---------------- fold BN into weights (log2e folded into Q path) ----------------
__global__ void fold_w_kernel(const float* __restrict__ wq, const float* __restrict__ wk,
    const float* __restrict__ wv,
    const float* gq, const float* bq, const float* mq, const float* vq,
    const float* gk, const float* bk, const float* mk, const float* vk,
    const float* gv, const float* bv, const float* mv, const float* vv,
    unsigned short* wqb, unsigned short* wkb, unsigned short* wvb,
    float* biasq, float* biask, float* biasv){
  int i = blockIdx.x*256 + threadIdx.x;   // 65536 threads
  int o = i >> 8;
  float sv = gv[o]*rsqrtf(vv[o]+1e-5f);
  wvb[i] = f2b(wv[i]*sv);
  if (i < 32*256){
    int oq = i >> 8;
    float sq = gq[oq]*rsqrtf(vq[oq]+1e-5f);
    wqb[i] = f2b(wq[i]*sq*LOG2E);
    float sk = gk[oq]*rsqrtf(vk[oq]+1e-5f);
    wkb[i] = f2b(wk[i]*sk);
  }
  if (i < 256) biasv[i] = bv[i] - mv[i]*(gv[i]*rsqrtf(vv[i]+1e-5f));
  if (i < 32){
    biasq[i] = (bq[i] - mq[i]*(gq[i]*rsqrtf(vq[i]+1e-5f)))*LOG2E;
    biask[i] = bk[i] - mk[i]*(gk[i]*rsqrtf(vk[i]+1e-5f));
  }
}

// ---------------- bilinear upsample 32x32 -> 64x64 (half-pixel, clamped) ----------------
__global__ void upsample_kernel(const float* __restrict__ x1, float* __restrict__ x1u){
  int idx = blockIdx.x*256 + threadIdx.x;       // B*C*64*64 = 4194304
  int x = idx & 63, y = (idx >> 6) & 63, bc = idx >> 12;
  float fy = 0.5f*y - 0.25f, fx = 0.5f*x - 0.25f;
  float y0f = floorf(fy), x0f = floorf(fx);
  float wy = fy - y0f, wx = fx - x0f;
  int y0 = max(0, min(31, (int)y0f)), y1 = max(0, min(31, (int)y0f + 1));
  int x0 = max(0, min(31, (int)x0f)), x1i = max(0, min(31, (int)x0f + 1));
  const float* s = x1 + (size_t)bc*1024;
  float v00 = s[y0*32+x0], v01 = s[y0*32+x1i];
  float v10 = s[y1*32+x0], v11 = s[y1*32+x1i];
  float v0 = v00 + wx*(v01-v00);
  float v1 = v10 + wx*(v11-v10);
  x1u[idx] = v0 + wy*(v1-v0);
}

// ---------------- transpose [B][C][N] f32 -> [B][N][C] bf16 ----------------
__global__ void transpose_bf_kernel(const float* __restrict__ X, unsigned short* __restrict__ Xt){
  __shared__ float tile[64][65];
  int b = blockIdx.z;
  int c0 = blockIdx.y*64, n0 = blockIdx.x*64;
  int t = threadIdx.x;
  int a = t & 63, q = t >> 6;
  #pragma unroll
  for (int i=0;i<16;i++){
    int c = q + i*4;
    tile[c][a] = X[(size_t)(b*C_ + c0 + c)*N_ + n0 + a];
  }
  __syncthreads();
  #pragma unroll
  for (int i=0;i<16;i++){
    int n = q + i*4;
    Xt[(size_t)(b*N_ + n0 + n)*C_ + c0 + a] = f2b(tile[a][n]);
  }
}

// ---------------- 1x1 conv + bias + lrelu as MFMA GEMM ----------------
template<int O, bool CN>
__global__ void conv_mfma_kernel(const unsigned short* __restrict__ Xt,
                                 const unsigned short* __restrict__ Wb,
                                 const float* __restrict__ bias,
                                 unsigned short* __restrict__ out){
  int b = blockIdx.y;
  int t = threadIdx.x, lane = t & 63, w = t >> 6;
  int l15 = lane & 15, g = lane >> 4;
  int m0 = blockIdx.x*64 + w*16;
  const unsigned short* xrow = Xt + (size_t)(b*N_ + m0 + l15)*C_ + g*8;
  short8 a[8];
  #pragma unroll
  for (int kk=0;kk<8;kk++) a[kk] = *(const short8*)(xrow + kk*32);
  #pragma unroll
  for (int ot=0; ot<O/16; ot++){
    int o = ot*16 + l15;
    const unsigned short* wrow = Wb + (size_t)o*C_ + g*8;
    float4v acc = {0.f,0.f,0.f,0.f};
    #pragma unroll
    for (int kk=0;kk<8;kk++){
      short8 bfr = *(const short8*)(wrow + kk*32);
      acc = __builtin_amdgcn_mfma_f32_16x16x32_bf16(a[kk], bfr, acc, 0, 0, 0);
    }
    float bs = bias[o];
    #pragma unroll
    for (int r=0;r<4;r++){
      float y = acc[r] + bs;
      y = y >= 0.f ? y : 0.1f*y;
      int m = m0 + g*4 + r;
      if (CN) out[(size_t)(b*O + o)*N_ + m] = f2b(y);
      else    out[(size_t)(b*N_ + m)*O + o] = f2b(y);
    }
  }
}

// ---------------- fused flash attention + gamma*out + x1u ----------------
// 8 waves: wm = w&3 (m sub-tile, 16 rows), ng = w>>2 (n-range half).
// Swapped QK^T (S^T = mfma(K,Q)) -> lane owns row m=l15. log2-domain softmax.
// Register-prefetched V (16 x short8) and K (2 x short8), 1 tile ahead.
__global__ __launch_bounds__(512, 2)
void attn_kernel(const unsigned short* __restrict__ Qb,
                 const unsigned short* __restrict__ Kb,
                 const unsigned short* __restrict__ Vb,
                 const float* __restrict__ x1u,
                 const float* __restrict__ gamma_p,
                 float* __restrict__ out){
  __shared__ unsigned short p_lds[8][16*40];   // per-wave P tile [16m][32n], stride 40
  __shared__ float o4[2][64][66];              // per-group partial O chunk [m][64c]
  __shared__ float stats[2][64][2];            // per-group (m, l) per row
  __shared__ float ML[64][2];                  // combined (M, L) per row
  int b = blockIdx.y;
  int t = threadIdx.x, lane = t & 63, w = t >> 6;
  int wm = w & 3, ng = w >> 2;
  int l15 = lane & 15, g = lane >> 4;
  int m0 = blockIdx.x*64 + wm*16;

  short8 qf = *(const short8*)(Qb + (size_t)(b*N_ + m0 + l15)*32 + g*8);

  float4v acc[16];
  #pragma unroll
  for (int ct=0;ct<16;ct++) acc[ct] = (float4v){0.f,0.f,0.f,0.f};
  float mrun = -1e30f, lrun = 0.f;
  unsigned short* pl = p_lds[w];
  const float4v zero4 = {0.f,0.f,0.f,0.f};

  const unsigned short* Kbase = Kb + (size_t)(b*N_ + ng*2048 + l15)*32 + g*8;
  const unsigned short* Vbase = Vb + (size_t)(b*C_ + l15)*N_ + ng*2048 + g*8;

  // compute body for one 32-n tile
  auto compute = [&](const short8 k0, const short8 k1, const short8 (&vf)[16]){
    float4v s0 = __builtin_amdgcn_mfma_f32_16x16x32_bf16(k0, qf, zero4, 0, 0, 0);
    float4v s1 = __builtin_amdgcn_mfma_f32_16x16x32_bf16(k1, qf, zero4, 0, 0, 0);
    float tmx = fmaxf(fmaxf(fmaxf(s0[0],s0[1]),fmaxf(s0[2],s0[3])),
                      fmaxf(fmaxf(s1[0],s1[1]),fmaxf(s1[2],s1[3])));
    if (__any((tmx > mrun + 8.f) ? 1 : 0)){
      float tm = fmaxf(tmx, __shfl_xor(tmx, 16));
      tm = fmaxf(tm, __shfl_xor(tm, 32));
      float mnew = fmaxf(mrun, tm);
      float sc = exp2f(mrun - mnew);
      float scr[4];
      #pragma unroll
      for (int r=0;r<4;r++) scr[r] = __shfl(sc, g*4 + r);
      lrun *= sc;
      mrun = mnew;
      #pragma unroll
      for (int ct=0;ct<16;ct++){
        #pragma unroll
        for (int r=0;r<4;r++) acc[ct][r] *= scr[r];
      }
    }
    float p0[4], p1[4];
    #pragma unroll
    for (int r=0;r<4;r++){
      p0[r] = exp2f(s0[r] - mrun);
      p1[r] = exp2f(s1[r] - mrun);
      lrun += p0[r] + p1[r];
    }
    unsigned a0 = (unsigned)f2b(p0[0]) | ((unsigned)f2b(p0[1]) << 16);
    unsigned a1 = (unsigned)f2b(p0[2]) | ((unsigned)f2b(p0[3]) << 16);
    unsigned b0 = (unsigned)f2b(p1[0]) | ((unsigned)f2b(p1[1]) << 16);
    unsigned b1 = (unsigned)f2b(p1[2]) | ((unsigned)f2b(p1[3]) << 16);
    *(uint2v*)((char*)pl + l15*80 + g*8)      = (uint2v){a0, a1};
    *(uint2v*)((char*)pl + l15*80 + 32 + g*8) = (uint2v){b0, b1};
    short8 pa = *(const short8*)((const char*)pl + l15*80 + g*16);
    #pragma unroll
    for (int ct=0;ct<16;ct++)
      acc[ct] = __builtin_amdgcn_mfma_f32_16x16x32_bf16(pa, vf[ct], acc[ct], 0, 0, 0);
  };

  // prefetch tile 0 into A set
  short8 kA0 = *(const short8*)(Kbase);
  short8 kA1 = *(const short8*)(Kbase + 512);
  short8 vA[16], vB[16];
  #pragma unroll
  for (int ct=0;ct<16;ct++) vA[ct] = *(const short8*)(Vbase + (size_t)ct*16*N_);
  short8 kB0, kB1;

  for (int it=0; it<32; ++it){
    int tb = 2*it + 1, tc = (2*it + 2) & 63;
    // issue prefetch tile tb into B
    kB0 = *(const short8*)(Kbase + (size_t)tb*1024);
    kB1 = *(const short8*)(Kbase + (size_t)tb*1024 + 512);
    #pragma unroll
    for (int ct=0;ct<16;ct++) vB[ct] = *(const short8*)(Vbase + (size_t)ct*16*N_ + tb*32);
    compute(kA0, kA1, vA);
    // issue prefetch tile tc into A
    kA0 = *(const short8*)(Kbase + (size_t)tc*1024);
    kA1 = *(const short8*)(Kbase + (size_t)tc*1024 + 512);
    #pragma unroll
    for (int ct=0;ct<16;ct++) vA[ct] = *(const short8*)(Vbase + (size_t)ct*16*N_ + tc*32);
    compute(kB0, kB1, vB);
  }

  // cross-lane l reduce (row l15), publish per-group stats
  lrun += __shfl_xor(lrun, 16);
  lrun += __shfl_xor(lrun, 32);
  if (g == 0){
    stats[ng][wm*16 + l15][0] = mrun;
    stats[ng][wm*16 + l15][1] = lrun;
  }
  __syncthreads();
  if (t < 64){
    float M = fmaxf(stats[0][t][0], stats[1][t][0]);
    float L = stats[0][t][1]*exp2f(stats[0][t][0]-M)
            + stats[1][t][1]*exp2f(stats[1][t][0]-M);
    ML[t][0] = M; ML[t][1] = L;
  }
  __syncthreads();
  // per-acc-row factor: rows m = wm*16 + g*4 + r
  float mr[4], fac[4];
  #pragma unroll
  for (int r=0;r<4;r++) mr[r] = __shfl(mrun, g*4 + r);
  #pragma unroll
  for (int r=0;r<4;r++){
    int row = wm*16 + g*4 + r;
    fac[r] = exp2f(mr[r] - ML[row][0]) / ML[row][1];
  }

  float gm = gamma_p[0];
  int m_l = t & 63, cq = t >> 6;   // cq 0..7
  #pragma unroll
  for (int cc=0; cc<4; cc++){
    #pragma unroll
    for (int ct2=0; ct2<4; ct2++){
      #pragma unroll
      for (int r=0;r<4;r++)
        o4[ng][wm*16 + g*4 + r][ct2*16 + l15] = acc[cc*4+ct2][r]*fac[r];
    }
    __syncthreads();
    #pragma unroll
    for (int i=0;i<8;i++){
      int c_l = cq + i*8;
      float v = o4[0][m_l][c_l] + o4[1][m_l][c_l];
      size_t gidx = (size_t)(b*C_ + cc*64 + c_l)*N_ + blockIdx.x*64 + m_l;
      out[gidx] = gm*v + x1u[gidx];
    }
    __syncthreads();
  }
}

extern "C" void kernel_launch(void* const* d_in, const int* in_sizes, int n_in,
                              void* d_out, int out_size, void* d_ws, size_t ws_size,
                              hipStream_t stream){
  (void)in_sizes; (void)n_in; (void)out_size; (void)ws_size;
  const float* x1 = (const float*)d_in[0];
  const float* x2 = (const float*)d_in[1];
  const float* wq = (const float*)d_in[2];
  const float* wk = (const float*)d_in[3];
  const float* wv = (const float*)d_in[4];
  const float* gq = (const float*)d_in[5];
  const float* bq = (const float*)d_in[6];
  const float* mq = (const float*)d_in[7];
  const float* vq = (const float*)d_in[8];
  const float* gk = (const float*)d_in[9];
  const float* bk = (const float*)d_in[10];
  const float* mk = (const float*)d_in[11];
  const float* vk = (const float*)d_in[12];
  const float* gv = (const float*)d_in[13];
  const float* bv = (const float*)d_in[14];
  const float* mv = (const float*)d_in[15];
  const float* vv = (const float*)d_in[16];
  const float* gamma = (const float*)d_in[17];
  float* out = (float*)d_out;

  char* p = (char*)d_ws;
  float* x1u          = (float*)p;          p += (size_t)B_*C_*N_*4;   // 16 MB
  unsigned short* x1t = (unsigned short*)p; p += (size_t)B_*N_*C_*2;   // 8 MB
  unsigned short* x2t = (unsigned short*)p; p += (size_t)B_*N_*C_*2;   // 8 MB
  unsigned short* Qb  = (unsigned short*)p; p += (size_t)B_*N_*32*2;   // 1 MB
  unsigned short* Kb  = (unsigned short*)p; p += (size_t)B_*N_*32*2;   // 1 MB
  unsigned short* Vb  = (unsigned short*)p; p += (size_t)B_*C_*N_*2;   // 8 MB
  unsigned short* wqb = (unsigned short*)p; p += 32*256*2;
  unsigned short* wkb = (unsigned short*)p; p += 32*256*2;
  unsigned short* wvb = (unsigned short*)p; p += 256*256*2;
  float* biasq        = (float*)p;          p += 32*4;
  float* biask        = (float*)p;          p += 32*4;
  float* biasv        = (float*)p;          p += 256*4;

  fold_w_kernel<<<256, 256, 0, stream>>>(wq,wk,wv,gq,bq,mq,vq,gk,bk,mk,vk,gv,bv,mv,vv,
                                         wqb,wkb,wvb,biasq,biask,biasv);
  upsample_kernel<<<16384, 256, 0, stream>>>(x1, x1u);
  transpose_bf_kernel<<<dim3(64,4,4), 256, 0, stream>>>(x1u, x1t);
  transpose_bf_kernel<<<dim3(64,4,4), 256, 0, stream>>>(x2, x2t);
  conv_mfma_kernel<32,false><<<dim3(64,4), 256, 0, stream>>>(x1t, wqb, biasq, Qb);
  conv_mfma_kernel<32,false><<<dim3(64,4), 256, 0, stream>>>(x2t, wkb, biask, Kb);
  conv_mfma_kernel<256,true><<<dim3(64,4), 256, 0, stream>>>(x2t, wvb, biasv, Vb);
  attn_kernel<<<dim3(64,4), 512, 0, stream>>>(Qb, Kb, Vb, x1u, gamma, out);
}

// Round 4
// 165.309 us; speedup vs baseline: 1.8909x; 1.8909x over previous
//
#include <hip/hip_runtime.h>

#define B_ 4
#define C_ 256
#define N_ 4096
#define LOG2E 1.4426950408889634f

typedef short short8 __attribute__((ext_vector_type(8)));
typedef float float4v __attribute__((ext_vector_type(4)));
typedef unsigned int uint2v __attribute__((ext_vector_type(2)));
typedef unsigned int u32;

__device__ inline unsigned short f2b(float x){
  unsigned u = __builtin_bit_cast(unsigned, x);
  u = u + 0x7FFFu + ((u >> 16) & 1u);
  return (unsigned short)(u >> 16);
}

__device__ inline void gload16(const void* g, void* l){
  __builtin_amdgcn_global_load_lds((const __attribute__((address_space(1))) u32*)g,
                                   (__attribute__((address_space(3))) u32*)l, 16, 0, 0);
}

// ---------------- fold BN into weights (log2e folded into Q path) ----------------
__global__ void fold_w_kernel(const float* __restrict__ wq, const float* __restrict__ wk,
    const float* __restrict__ wv,
    const float* gq, const float* bq, const float* mq, const float* vq,
    const float* gk, const float* bk, const float* mk, const float* vk,
    const float* gv, const float* bv, const float* mv, const float* vv,
    unsigned short* wqb, unsigned short* wkb, unsigned short* wvb,
    float* biasq, float* biask, float* biasv){
  int i = blockIdx.x*256 + threadIdx.x;   // 65536 threads
  int o = i >> 8;
  float sv = gv[o]*rsqrtf(vv[o]+1e-5f);
  wvb[i] = f2b(wv[i]*sv);
  if (i < 32*256){
    int oq = i >> 8;
    float sq = gq[oq]*rsqrtf(vq[oq]+1e-5f);
    wqb[i] = f2b(wq[i]*sq*LOG2E);
    float sk = gk[oq]*rsqrtf(vk[oq]+1e-5f);
    wkb[i] = f2b(wk[i]*sk);
  }
  if (i < 256) biasv[i] = bv[i] - mv[i]*(gv[i]*rsqrtf(vv[i]+1e-5f));
  if (i < 32){
    biasq[i] = (bq[i] - mq[i]*(gq[i]*rsqrtf(vq[i]+1e-5f)))*LOG2E;
    biask[i] = bk[i] - mk[i]*(gk[i]*rsqrtf(vk[i]+1e-5f));
  }
}

// ------- fused bilinear upsample 32x32->64x64 + write x1u (f32) + x1t ([B][N][C] bf16) -------
__global__ void upsample_tr_kernel(const float* __restrict__ x1, float* __restrict__ x1u,
                                   unsigned short* __restrict__ x1t){
  __shared__ float tile[64][65];
  int y = blockIdx.x; int c0 = blockIdx.y*64; int b = blockIdx.z;
  int t = threadIdx.x;
  float fy = 0.5f*y - 0.25f;
  float y0f = floorf(fy); float wy = fy - y0f;
  int y0 = max(0, min(31, (int)y0f)), y1 = max(0, min(31, (int)y0f+1));
  int x = t & 63, cg = t >> 6;
  float fx = 0.5f*x - 0.25f;
  float x0f = floorf(fx); float wx = fx - x0f;
  int x0 = max(0, min(31,(int)x0f)), x1i = max(0, min(31,(int)x0f+1));
  #pragma unroll
  for (int i=0;i<16;i++){
    int c = cg + i*4;
    const float* s = x1 + ((size_t)(b*C_ + c0 + c))*1024;
    float v00=s[y0*32+x0], v01=s[y0*32+x1i], v10=s[y1*32+x0], v11=s[y1*32+x1i];
    float v0 = v00 + wx*(v01-v00), v1 = v10 + wx*(v11-v10);
    float val = v0 + wy*(v1-v0);
    x1u[((size_t)(b*C_ + c0 + c))*N_ + y*64 + x] = val;
    tile[c][x] = val;
  }
  __syncthreads();
  int cl = t & 63, xg = t >> 6;
  #pragma unroll
  for (int i=0;i<16;i++){
    int xx = xg + i*4;
    x1t[((size_t)(b*N_) + y*64 + xx)*C_ + c0 + cl] = f2b(tile[cl][xx]);
  }
}

// ---------------- transpose [B][C][N] f32 -> [B][N][C] bf16 (for x2) ----------------
__global__ void transpose_bf_kernel(const float* __restrict__ X, unsigned short* __restrict__ Xt){
  __shared__ float tile[64][65];
  int b = blockIdx.z;
  int c0 = blockIdx.y*64, n0 = blockIdx.x*64;
  int t = threadIdx.x;
  int a = t & 63, q = t >> 6;
  #pragma unroll
  for (int i=0;i<16;i++){
    int c = q + i*4;
    tile[c][a] = X[(size_t)(b*C_ + c0 + c)*N_ + n0 + a];
  }
  __syncthreads();
  #pragma unroll
  for (int i=0;i<16;i++){
    int n = q + i*4;
    Xt[(size_t)(b*N_ + n0 + n)*C_ + c0 + a] = f2b(tile[a][n]);
  }
}

// ---------------- 1x1 conv + bias + lrelu as MFMA GEMM ----------------
template<int O, bool CN>
__global__ void conv_mfma_kernel(const unsigned short* __restrict__ Xt,
                                 const unsigned short* __restrict__ Wb,
                                 const float* __restrict__ bias,
                                 unsigned short* __restrict__ out){
  int b = blockIdx.y;
  int t = threadIdx.x, lane = t & 63, w = t >> 6;
  int l15 = lane & 15, g = lane >> 4;
  int m0 = blockIdx.x*64 + w*16;
  const unsigned short* xrow = Xt + (size_t)(b*N_ + m0 + l15)*C_ + g*8;
  short8 a[8];
  #pragma unroll
  for (int kk=0;kk<8;kk++) a[kk] = *(const short8*)(xrow + kk*32);
  #pragma unroll
  for (int ot=0; ot<O/16; ot++){
    int o = ot*16 + l15;
    const unsigned short* wrow = Wb + (size_t)o*C_ + g*8;
    float4v acc = {0.f,0.f,0.f,0.f};
    #pragma unroll
    for (int kk=0;kk<8;kk++){
      short8 bfr = *(const short8*)(wrow + kk*32);
      acc = __builtin_amdgcn_mfma_f32_16x16x32_bf16(a[kk], bfr, acc, 0, 0, 0);
    }
    float bs = bias[o];
    #pragma unroll
    for (int r=0;r<4;r++){
      float y = acc[r] + bs;
      y = y >= 0.f ? y : 0.1f*y;
      int m = m0 + g*4 + r;
      if (CN) out[(size_t)(b*O + o)*N_ + m] = f2b(y);
      else    out[(size_t)(b*N_ + m)*O + o] = f2b(y);
    }
  }
}

// ---------------- fused flash attention + gamma*out + x1u ----------------
// 4 waves, grid (64 m-blocks, 4 b). Wave w: owns softmax of m-tile w (16 rows),
// and the PV/output c-range [w*64, w*64+64) for ALL 64 m-rows (c-split).
// V tile [256c][64n] staged in LDS via global_load_lds, double-buffered,
// XOR-swizzled (chunk ^= row&7). P tiles shared via LDS (same swizzle).
__global__ __launch_bounds__(256, 1)
void attn_kernel(const unsigned short* __restrict__ Qb,
                 const unsigned short* __restrict__ Kb,
                 const unsigned short* __restrict__ Vb,
                 const float* __restrict__ x1u,
                 const float* __restrict__ gamma_p,
                 float* __restrict__ out){
  __shared__ __align__(16) char smem[74256];
  char* vbuf0 = smem;                         // 2 x 32768 V double-buffer
  char* vbuf1 = smem + 32768;
  char* pbase = smem + 65536;                 // 4 x 2048 P tiles
  float* scl  = (float*)(smem + 73728);       // 4 x 16 rescale factors
  float* lst  = (float*)(smem + 73984);       // 64 row sums
  int* flags  = (int*)(smem + 74240);         // 4 rescale flags

  int b = blockIdx.y;
  int t = threadIdx.x, lane = t & 63, w = t >> 6;
  int l15 = lane & 15, g = lane >> 4;
  int m0 = blockIdx.x*64 + w*16;
  int swz = (l15 & 7) << 4;

  short8 qf = *(const short8*)(Qb + (size_t)(b*N_ + m0 + l15)*32 + g*8);

  float4v acc[4][4];   // [mt][ct]
  #pragma unroll
  for (int mt=0;mt<4;mt++)
    #pragma unroll
    for (int ct=0;ct<4;ct++) acc[mt][ct] = (float4v){0.f,0.f,0.f,0.f};
  float mrow = -1e30f, lrun = 0.f;
  const float4v zero4 = {0.f,0.f,0.f,0.f};

  // staging offsets: chunk i = j*256 + w*64 + lane; row c = i>>3; jj = i&7
  size_t goff[8]; int loff[8];
  #pragma unroll
  for (int j=0;j<8;j++){
    int i = j*256 + w*64 + lane;
    int c = i >> 3, jj = i & 7;
    loff[j] = i*16;
    goff[j] = (size_t)(b*C_ + c)*(N_*2) + ((size_t)((jj ^ (c & 7)) << 4));
  }
  const char* Vbyte = (const char*)Vb;

  auto stageV = [&](int tt, char* buf){
    const char* src = Vbyte + tt*128;          // n0*2 bytes
    #pragma unroll
    for (int j=0;j<8;j++) gload16(src + goff[j], buf + loff[j]);
  };
  auto loadK = [&](short8 (&kf)[4], int tt){
    const unsigned short* kp = Kb + (size_t)(b*N_ + tt*64 + l15)*32 + g*8;
    #pragma unroll
    for (int j=0;j<4;j++) kf[j] = *(const short8*)(kp + j*512);
  };

  auto body = [&](int tt, char* vb, short8 (&kfC)[4], short8 (&kfN)[4], int tn, char* nb){
    // S^T = mfma(K, Q): lane owns row m = l15; n = j*16 + g*4 + r
    float4v s[4];
    #pragma unroll
    for (int j=0;j<4;j++)
      s[j] = __builtin_amdgcn_mfma_f32_16x16x32_bf16(kfC[j], qf, zero4, 0, 0, 0);
    float tmax = fmaxf(fmaxf(fmaxf(s[0][0],s[0][1]),fmaxf(s[0][2],s[0][3])),
               fmaxf(fmaxf(fmaxf(s[1][0],s[1][1]),fmaxf(s[1][2],s[1][3])),
               fmaxf(fmaxf(fmaxf(s[2][0],s[2][1]),fmaxf(s[2][2],s[2][3])),
                     fmaxf(fmaxf(s[3][0],s[3][1]),fmaxf(s[3][2],s[3][3])))));
    int trig = __any((tmax > mrow + 8.f) ? 1 : 0) ? 1 : 0;
    if (lane == 0) flags[w] = trig;
    if (trig){
      float tm = fmaxf(tmax, __shfl_xor(tmax, 16));
      tm = fmaxf(tm, __shfl_xor(tm, 32));
      float mnew = fmaxf(mrow, tm);
      float sc = exp2f(mrow - mnew);
      mrow = mnew; lrun *= sc;
      if (lane < 16) scl[w*16 + l15] = sc;
    }
    char* pw = pbase + w*2048 + l15*128;
    #pragma unroll
    for (int j=0;j<4;j++){
      float p0 = exp2f(s[j][0]-mrow), p1 = exp2f(s[j][1]-mrow);
      float p2 = exp2f(s[j][2]-mrow), p3 = exp2f(s[j][3]-mrow);
      lrun += (p0+p1)+(p2+p3);
      u32 lo = (u32)f2b(p0) | ((u32)f2b(p1)<<16);
      u32 hi = (u32)f2b(p2) | ((u32)f2b(p3)<<16);
      *(uint2v*)(pw + ((j*32 + g*8) ^ swz)) = (uint2v){lo, hi};
    }
    __syncthreads();   // P + flags + scl visible; V tile (this buf) was drained last barrier
    if (tn < 64){ stageV(tn, nb); loadK(kfN, tn); }
    __builtin_amdgcn_sched_barrier(0);
    int f0 = flags[0], f1 = flags[1], f2 = flags[2], f3 = flags[3];
    if (f0){ float4v sv = *(float4v*)((char*)scl + g*16);
      #pragma unroll
      for (int ct=0;ct<4;ct++){ acc[0][ct][0]*=sv[0]; acc[0][ct][1]*=sv[1]; acc[0][ct][2]*=sv[2]; acc[0][ct][3]*=sv[3]; } }
    if (f1){ float4v sv = *(float4v*)((char*)scl + 64 + g*16);
      #pragma unroll
      for (int ct=0;ct<4;ct++){ acc[1][ct][0]*=sv[0]; acc[1][ct][1]*=sv[1]; acc[1][ct][2]*=sv[2]; acc[1][ct][3]*=sv[3]; } }
    if (f2){ float4v sv = *(float4v*)((char*)scl + 128 + g*16);
      #pragma unroll
      for (int ct=0;ct<4;ct++){ acc[2][ct][0]*=sv[0]; acc[2][ct][1]*=sv[1]; acc[2][ct][2]*=sv[2]; acc[2][ct][3]*=sv[3]; } }
    if (f3){ float4v sv = *(float4v*)((char*)scl + 192 + g*16);
      #pragma unroll
      for (int ct=0;ct<4;ct++){ acc[3][ct][0]*=sv[0]; acc[3][ct][1]*=sv[1]; acc[3][ct][2]*=sv[2]; acc[3][ct][3]*=sv[3]; } }
    // PV: acc[mt][ct] += P[mt] * V  (A = P rows m, B = V[k=n][col=c])
    #pragma unroll
    for (int kh=0; kh<2; kh++){
      int ko = (kh*64 + g*16) ^ swz;
      short8 pa0 = *(const short8*)(pbase +      l15*128 + ko);
      short8 pa1 = *(const short8*)(pbase + 2048 + l15*128 + ko);
      short8 pa2 = *(const short8*)(pbase + 4096 + l15*128 + ko);
      short8 pa3 = *(const short8*)(pbase + 6144 + l15*128 + ko);
      #pragma unroll
      for (int ct=0; ct<4; ct++){
        short8 vf = *(const short8*)(vb + (w*64 + ct*16 + l15)*128 + ko);
        acc[0][ct] = __builtin_amdgcn_mfma_f32_16x16x32_bf16(pa0, vf, acc[0][ct], 0, 0, 0);
        acc[1][ct] = __builtin_amdgcn_mfma_f32_16x16x32_bf16(pa1, vf, acc[1][ct], 0, 0, 0);
        acc[2][ct] = __builtin_amdgcn_mfma_f32_16x16x32_bf16(pa2, vf, acc[2][ct], 0, 0, 0);
        acc[3][ct] = __builtin_amdgcn_mfma_f32_16x16x32_bf16(pa3, vf, acc[3][ct], 0, 0, 0);
      }
    }
    __syncthreads();   // PV done (P may be overwritten; other buf stage drained)
  };

  short8 kfA[4], kfB[4];
  stageV(0, vbuf0); loadK(kfA, 0);
  __syncthreads();
  for (int tt=0; tt<64; tt+=2){
    body(tt,   vbuf0, kfA, kfB, tt+1, vbuf1);
    body(tt+1, vbuf1, kfB, kfA, tt+2, vbuf0);
  }

  // epilogue: final row sums, normalize, transpose via LDS overlay, fused residual
  lrun += __shfl_xor(lrun, 16);
  lrun += __shfl_xor(lrun, 32);
  if (lane < 16) lst[w*16 + l15] = lrun;
  __syncthreads();
  float4v lv[4];
  #pragma unroll
  for (int mt=0;mt<4;mt++) lv[mt] = *(float4v*)((char*)lst + mt*64 + g*16);
  float gm = gamma_p[0];
  float* ow = (float*)smem + w*4224;   // 64 x 66 f32 per wave (overlays v/p bufs)
  #pragma unroll
  for (int mt=0;mt<4;mt++){
    #pragma unroll
    for (int ct=0;ct<4;ct++){
      #pragma unroll
      for (int r=0;r<4;r++)
        ow[(mt*16 + g*4 + r)*66 + ct*16 + l15] = acc[mt][ct][r] / lv[mt][r];
    }
  }
  __syncthreads();
  const float* xr = x1u + (size_t)(b*C_ + w*64)*N_ + blockIdx.x*64;
  float* orow = out + (size_t)(b*C_ + w*64)*N_ + blockIdx.x*64;
  #pragma unroll 4
  for (int cl=0; cl<64; cl++){
    float v = ow[lane*66 + cl];
    orow[(size_t)cl*N_ + lane] = gm*v + xr[(size_t)cl*N_ + lane];
  }
}

extern "C" void kernel_launch(void* const* d_in, const int* in_sizes, int n_in,
                              void* d_out, int out_size, void* d_ws, size_t ws_size,
                              hipStream_t stream){
  (void)in_sizes; (void)n_in; (void)out_size; (void)ws_size;
  const float* x1 = (const float*)d_in[0];
  const float* x2 = (const float*)d_in[1];
  const float* wq = (const float*)d_in[2];
  const float* wk = (const float*)d_in[3];
  const float* wv = (const float*)d_in[4];
  const float* gq = (const float*)d_in[5];
  const float* bq = (const float*)d_in[6];
  const float* mq = (const float*)d_in[7];
  const float* vq = (const float*)d_in[8];
  const float* gk = (const float*)d_in[9];
  const float* bk = (const float*)d_in[10];
  const float* mk = (const float*)d_in[11];
  const float* vk = (const float*)d_in[12];
  const float* gv = (const float*)d_in[13];
  const float* bv = (const float*)d_in[14];
  const float* mv = (const float*)d_in[15];
  const float* vv = (const float*)d_in[16];
  const float* gamma = (const float*)d_in[17];
  float* out = (float*)d_out;

  char* p = (char*)d_ws;
  float* x1u          = (float*)p;          p += (size_t)B_*C_*N_*4;   // 16 MB
  unsigned short* x1t = (unsigned short*)p; p += (size_t)B_*N_*C_*2;   // 8 MB
  unsigned short* x2t = (unsigned short*)p; p += (size_t)B_*N_*C_*2;   // 8 MB
  unsigned short* Qb  = (unsigned short*)p; p += (size_t)B_*N_*32*2;   // 1 MB
  unsigned short* Kb  = (unsigned short*)p; p += (size_t)B_*N_*32*2;   // 1 MB
  unsigned short* Vb  = (unsigned short*)p; p += (size_t)B_*C_*N_*2;   // 8 MB
  unsigned short* wqb = (unsigned short*)p; p += 32*256*2;
  unsigned short* wkb = (unsigned short*)p; p += 32*256*2;
  unsigned short* wvb = (unsigned short*)p; p += 256*256*2;
  float* biasq        = (float*)p;          p += 32*4;
  float* biask        = (float*)p;          p += 32*4;
  float* biasv        = (float*)p;          p += 256*4;

  fold_w_kernel<<<256, 256, 0, stream>>>(wq,wk,wv,gq,bq,mq,vq,gk,bk,mk,vk,gv,bv,mv,vv,
                                         wqb,wkb,wvb,biasq,biask,biasv);
  upsample_tr_kernel<<<dim3(64,4,4), 256, 0, stream>>>(x1, x1u, x1t);
  transpose_bf_kernel<<<dim3(64,4,4), 256, 0, stream>>>(x2, x2t);
  conv_mfma_kernel<32,false><<<dim3(64,4), 256, 0, stream>>>(x1t, wqb, biasq, Qb);
  conv_mfma_kernel<32,false><<<dim3(64,4), 256, 0, stream>>>(x2t, wkb, biask, Kb);
  conv_mfma_kernel<256,true><<<dim3(64,4), 256, 0, stream>>>(x2t, wvb, biasv, Vb);
  attn_kernel<<<dim3(64,4), 256, 0, stream>>>(Qb, Kb, Vb, x1u, gamma, out);
}

// Round 5
// 150.724 us; speedup vs baseline: 2.0739x; 1.0968x over previous
//
#include <hip/hip_runtime.h>

#define B_ 4
#define C_ 256
#define N_ 4096
#define LOG2E 1.4426950408889634f

typedef short short8 __attribute__((ext_vector_type(8)));
typedef float float4v __attribute__((ext_vector_type(4)));
typedef unsigned int uint2v __attribute__((ext_vector_type(2)));
typedef unsigned int u32;

__device__ inline unsigned short f2b(float x){
  unsigned u = __builtin_bit_cast(unsigned, x);
  u = u + 0x7FFFu + ((u >> 16) & 1u);
  return (unsigned short)(u >> 16);
}

__device__ inline u32 cvtpk(float lo, float hi){
  u32 r; asm("v_cvt_pk_bf16_f32 %0, %1, %2" : "=v"(r) : "v"(lo), "v"(hi)); return r;
}

__device__ inline void gload16(const void* g, void* l){
  __builtin_amdgcn_global_load_lds((const __attribute__((address_space(1))) u32*)g,
                                   (__attribute__((address_space(3))) u32*)l, 16, 0, 0);
}

// ---------------- fold BN into weights (log2e folded into Q path) ----------------
__global__ void fold_w_kernel(const float* __restrict__ wq, const float* __restrict__ wk,
    const float* __restrict__ wv,
    const float* gq, const float* bq, const float* mq, const float* vq,
    const float* gk, const float* bk, const float* mk, const float* vk,
    const float* gv, const float* bv, const float* mv, const float* vv,
    unsigned short* wqb, unsigned short* wkb, unsigned short* wvb,
    float* biasq, float* biask, float* biasv){
  int i = blockIdx.x*256 + threadIdx.x;   // 65536 threads
  int o = i >> 8;
  float sv = gv[o]*rsqrtf(vv[o]+1e-5f);
  wvb[i] = f2b(wv[i]*sv);
  if (i < 32*256){
    int oq = i >> 8;
    float sq = gq[oq]*rsqrtf(vq[oq]+1e-5f);
    wqb[i] = f2b(wq[i]*sq*LOG2E);
    float sk = gk[oq]*rsqrtf(vk[oq]+1e-5f);
    wkb[i] = f2b(wk[i]*sk);
  }
  if (i < 256) biasv[i] = bv[i] - mv[i]*(gv[i]*rsqrtf(vv[i]+1e-5f));
  if (i < 32){
    biasq[i] = (bq[i] - mq[i]*(gq[i]*rsqrtf(vq[i]+1e-5f)))*LOG2E;
    biask[i] = bk[i] - mk[i]*(gk[i]*rsqrtf(vk[i]+1e-5f));
  }
}

// ------- fused bilinear upsample 32x32->64x64 + write x1u (f32) + x1t ([B][N][C] bf16) -------
__global__ void upsample_tr_kernel(const float* __restrict__ x1, float* __restrict__ x1u,
                                   unsigned short* __restrict__ x1t){
  __shared__ float tile[64][65];
  int y = blockIdx.x; int c0 = blockIdx.y*64; int b = blockIdx.z;
  int t = threadIdx.x;
  float fy = 0.5f*y - 0.25f;
  float y0f = floorf(fy); float wy = fy - y0f;
  int y0 = max(0, min(31, (int)y0f)), y1 = max(0, min(31, (int)y0f+1));
  int x = t & 63, cg = t >> 6;
  float fx = 0.5f*x - 0.25f;
  float x0f = floorf(fx); float wx = fx - x0f;
  int x0 = max(0, min(31,(int)x0f)), x1i = max(0, min(31,(int)x0f+1));
  #pragma unroll
  for (int i=0;i<16;i++){
    int c = cg + i*4;
    const float* s = x1 + ((size_t)(b*C_ + c0 + c))*1024;
    float v00=s[y0*32+x0], v01=s[y0*32+x1i], v10=s[y1*32+x0], v11=s[y1*32+x1i];
    float v0 = v00 + wx*(v01-v00), v1 = v10 + wx*(v11-v10);
    float val = v0 + wy*(v1-v0);
    x1u[((size_t)(b*C_ + c0 + c))*N_ + y*64 + x] = val;
    tile[c][x] = val;
  }
  __syncthreads();
  int cl = t & 63, xg = t >> 6;
  #pragma unroll
  for (int i=0;i<16;i++){
    int xx = xg + i*4;
    x1t[((size_t)(b*N_) + y*64 + xx)*C_ + c0 + cl] = f2b(tile[cl][xx]);
  }
}

// ---------------- transpose [B][C][N] f32 -> [B][N][C] bf16 (for x2) ----------------
__global__ void transpose_bf_kernel(const float* __restrict__ X, unsigned short* __restrict__ Xt){
  __shared__ float tile[64][65];
  int b = blockIdx.z;
  int c0 = blockIdx.y*64, n0 = blockIdx.x*64;
  int t = threadIdx.x;
  int a = t & 63, q = t >> 6;
  #pragma unroll
  for (int i=0;i<16;i++){
    int c = q + i*4;
    tile[c][a] = X[(size_t)(b*C_ + c0 + c)*N_ + n0 + a];
  }
  __syncthreads();
  #pragma unroll
  for (int i=0;i<16;i++){
    int n = q + i*4;
    Xt[(size_t)(b*N_ + n0 + n)*C_ + c0 + a] = f2b(tile[a][n]);
  }
}

// ---------------- 1x1 conv + bias + lrelu as MFMA GEMM ----------------
template<int O, bool CN>
__global__ void conv_mfma_kernel(const unsigned short* __restrict__ Xt,
                                 const unsigned short* __restrict__ Wb,
                                 const float* __restrict__ bias,
                                 unsigned short* __restrict__ out){
  int b = blockIdx.y;
  int t = threadIdx.x, lane = t & 63, w = t >> 6;
  int l15 = lane & 15, g = lane >> 4;
  int m0 = blockIdx.x*64 + w*16;
  const unsigned short* xrow = Xt + (size_t)(b*N_ + m0 + l15)*C_ + g*8;
  short8 a[8];
  #pragma unroll
  for (int kk=0;kk<8;kk++) a[kk] = *(const short8*)(xrow + kk*32);
  #pragma unroll
  for (int ot=0; ot<O/16; ot++){
    int o = ot*16 + l15;
    const unsigned short* wrow = Wb + (size_t)o*C_ + g*8;
    float4v acc = {0.f,0.f,0.f,0.f};
    #pragma unroll
    for (int kk=0;kk<8;kk++){
      short8 bfr = *(const short8*)(wrow + kk*32);
      acc = __builtin_amdgcn_mfma_f32_16x16x32_bf16(a[kk], bfr, acc, 0, 0, 0);
    }
    float bs = bias[o];
    #pragma unroll
    for (int r=0;r<4;r++){
      float y = acc[r] + bs;
      y = y >= 0.f ? y : 0.1f*y;
      int m = m0 + g*4 + r;
      if (CN) out[(size_t)(b*O + o)*N_ + m] = f2b(y);
      else    out[(size_t)(b*N_ + m)*O + o] = f2b(y);
    }
  }
}

// ---------------- fused flash attention + gamma*out + x1u ----------------
// Grid (128 m-blocks of 32 rows, 4 b), 4 waves, 2 blocks/CU.
// Waves 0,1 own softmax of 16-row tiles 0,1; all 4 waves do PV for c-range w*64.
// V tile [256c][64n] staged in LDS via global_load_lds (all 4 waves), double-buffered,
// XOR-swizzled (chunk ^= row&7). P tiles shared via LDS (same swizzle).
__global__ __launch_bounds__(256, 2)
void attn_kernel(const unsigned short* __restrict__ Qb,
                 const unsigned short* __restrict__ Kb,
                 const unsigned short* __restrict__ Vb,
                 const float* __restrict__ x1u,
                 const float* __restrict__ gamma_p,
                 float* __restrict__ out){
  __shared__ __align__(16) char smem[69896];
  char* vbuf0 = smem;                         // 2 x 32768 V double-buffer
  char* vbuf1 = smem + 32768;
  char* pbase = smem + 65536;                 // 2 x 2048 P tiles
  float* scl  = (float*)(smem + 69632);       // 2 x 16 rescale factors
  float* lst  = (float*)(smem + 69760);       // 32 row sums
  int* flags  = (int*)(smem + 69888);         // 2 rescale flags

  int b = blockIdx.y;
  int t = threadIdx.x, lane = t & 63, w = t >> 6;
  int l15 = lane & 15, g = lane >> 4;
  int swz = (l15 & 7) << 4;
  int wm = w & 1;                  // softmax tile for waves 0,1

  short8 qf;
  if (w < 2)
    qf = *(const short8*)(Qb + (size_t)(b*N_ + blockIdx.x*32 + wm*16 + l15)*32 + g*8);

  float4v acc[2][4];   // [mt][ct]
  #pragma unroll
  for (int mt=0;mt<2;mt++)
    #pragma unroll
    for (int ct=0;ct<4;ct++) acc[mt][ct] = (float4v){0.f,0.f,0.f,0.f};
  float mrow = -1e30f, lrun = 0.f;
  const float4v zero4 = {0.f,0.f,0.f,0.f};

  // staging offsets: chunk i = j*256 + w*64 + lane; row c = i>>3; jj = i&7
  size_t goff[8]; int loff[8];
  #pragma unroll
  for (int j=0;j<8;j++){
    int i = j*256 + w*64 + lane;
    int c = i >> 3, jj = i & 7;
    loff[j] = i*16;
    goff[j] = (size_t)(b*C_ + c)*(N_*2) + ((size_t)((jj ^ (c & 7)) << 4));
  }
  const char* Vbyte = (const char*)Vb;

  auto stageV = [&](int tt, char* buf){
    const char* src = Vbyte + tt*128;          // n0*2 bytes
    #pragma unroll
    for (int j=0;j<8;j++) gload16(src + goff[j], buf + loff[j]);
  };
  auto loadK = [&](short8 (&kf)[4], int tt){
    const unsigned short* kp = Kb + (size_t)(b*N_ + tt*64 + l15)*32 + g*8;
    #pragma unroll
    for (int j=0;j<4;j++) kf[j] = *(const short8*)(kp + j*512);
  };

  auto body = [&](int tt, char* vb, short8 (&kfC)[4], short8 (&kfN)[4], int tn, char* nb){
    if (w < 2){
      // S^T = mfma(K, Q): lane owns row m = l15; n = j*16 + g*4 + r
      float4v s[4];
      #pragma unroll
      for (int j=0;j<4;j++)
        s[j] = __builtin_amdgcn_mfma_f32_16x16x32_bf16(kfC[j], qf, zero4, 0, 0, 0);
      float tmax = fmaxf(fmaxf(fmaxf(s[0][0],s[0][1]),fmaxf(s[0][2],s[0][3])),
                 fmaxf(fmaxf(fmaxf(s[1][0],s[1][1]),fmaxf(s[1][2],s[1][3])),
                 fmaxf(fmaxf(fmaxf(s[2][0],s[2][1]),fmaxf(s[2][2],s[2][3])),
                       fmaxf(fmaxf(s[3][0],s[3][1]),fmaxf(s[3][2],s[3][3])))));
      int trig = __any((tmax > mrow + 8.f) ? 1 : 0) ? 1 : 0;
      if (lane == 0) flags[wm] = trig;
      if (trig){
        float tm = fmaxf(tmax, __shfl_xor(tmax, 16));
        tm = fmaxf(tm, __shfl_xor(tm, 32));
        float mnew = fmaxf(mrow, tm);
        float sc = exp2f(mrow - mnew);
        mrow = mnew; lrun *= sc;
        if (lane < 16) scl[wm*16 + l15] = sc;
      }
      char* pw = pbase + wm*2048 + l15*128;
      #pragma unroll
      for (int j=0;j<4;j++){
        float p0 = exp2f(s[j][0]-mrow), p1 = exp2f(s[j][1]-mrow);
        float p2 = exp2f(s[j][2]-mrow), p3 = exp2f(s[j][3]-mrow);
        lrun += (p0+p1)+(p2+p3);
        u32 lo = cvtpk(p0, p1);
        u32 hi = cvtpk(p2, p3);
        *(uint2v*)(pw + ((j*32 + g*8) ^ swz)) = (uint2v){lo, hi};
      }
    }
    __syncthreads();   // P + flags + scl visible; next-buf reads all drained earlier
    if (tn < 64){ stageV(tn, nb); if (w < 2) loadK(kfN, tn); }
    __builtin_amdgcn_sched_barrier(0);
    int f0 = flags[0], f1 = flags[1];
    if (f0){ float4v sv = *(float4v*)((char*)scl + g*16);
      #pragma unroll
      for (int ct=0;ct<4;ct++){ acc[0][ct][0]*=sv[0]; acc[0][ct][1]*=sv[1]; acc[0][ct][2]*=sv[2]; acc[0][ct][3]*=sv[3]; } }
    if (f1){ float4v sv = *(float4v*)((char*)scl + 64 + g*16);
      #pragma unroll
      for (int ct=0;ct<4;ct++){ acc[1][ct][0]*=sv[0]; acc[1][ct][1]*=sv[1]; acc[1][ct][2]*=sv[2]; acc[1][ct][3]*=sv[3]; } }
    // PV: acc[mt][ct] += P[mt] * V  (A = P rows m, B = V[k=n][col=c])
    #pragma unroll
    for (int kh=0; kh<2; kh++){
      int ko = (kh*64 + g*16) ^ swz;
      short8 pa0 = *(const short8*)(pbase +        l15*128 + ko);
      short8 pa1 = *(const short8*)(pbase + 2048 + l15*128 + ko);
      #pragma unroll
      for (int ct=0; ct<4; ct++){
        short8 vf = *(const short8*)(vb + (w*64 + ct*16 + l15)*128 + ko);
        acc[0][ct] = __builtin_amdgcn_mfma_f32_16x16x32_bf16(pa0, vf, acc[0][ct], 0, 0, 0);
        acc[1][ct] = __builtin_amdgcn_mfma_f32_16x16x32_bf16(pa1, vf, acc[1][ct], 0, 0, 0);
      }
    }
    __syncthreads();   // PV done (P may be overwritten; other buf stage drained)
  };

  short8 kfA[4], kfB[4];
  stageV(0, vbuf0);
  if (w < 2) loadK(kfA, 0);
  __syncthreads();
  for (int tt=0; tt<64; tt+=2){
    body(tt,   vbuf0, kfA, kfB, tt+1, vbuf1);
    body(tt+1, vbuf1, kfB, kfA, tt+2, vbuf0);
  }

  // epilogue: final row sums, normalize, transpose via LDS overlay, fused residual
  if (w < 2){
    lrun += __shfl_xor(lrun, 16);
    lrun += __shfl_xor(lrun, 32);
    if (lane < 16) lst[wm*16 + l15] = lrun;
  }
  __syncthreads();
  float4v lv[2];
  #pragma unroll
  for (int mt=0;mt<2;mt++) lv[mt] = *(float4v*)((char*)lst + mt*64 + g*16);
  float gm = gamma_p[0];
  float* ow = (float*)smem + w*2112;   // 32 x 66 f32 per wave (overlays v bufs)
  #pragma unroll
  for (int mt=0;mt<2;mt++){
    #pragma unroll
    for (int ct=0;ct<4;ct++){
      #pragma unroll
      for (int r=0;r<4;r++)
        ow[(mt*16 + g*4 + r)*66 + ct*16 + l15] = acc[mt][ct][r] / lv[mt][r];
    }
  }
  __syncthreads();
  int m31 = lane & 31, ch = lane >> 5;
  const float* xr = x1u + (size_t)(b*C_ + w*64)*N_ + blockIdx.x*32;
  float* orow = out + (size_t)(b*C_ + w*64)*N_ + blockIdx.x*32;
  #pragma unroll 8
  for (int i=0; i<32; i++){
    int c_l = i*2 + ch;
    float v = ow[m31*66 + c_l];
    orow[(size_t)c_l*N_ + m31] = gm*v + xr[(size_t)c_l*N_ + m31];
  }
}

extern "C" void kernel_launch(void* const* d_in, const int* in_sizes, int n_in,
                              void* d_out, int out_size, void* d_ws, size_t ws_size,
                              hipStream_t stream){
  (void)in_sizes; (void)n_in; (void)out_size; (void)ws_size;
  const float* x1 = (const float*)d_in[0];
  const float* x2 = (const float*)d_in[1];
  const float* wq = (const float*)d_in[2];
  const float* wk = (const float*)d_in[3];
  const float* wv = (const float*)d_in[4];
  const float* gq = (const float*)d_in[5];
  const float* bq = (const float*)d_in[6];
  const float* mq = (const float*)d_in[7];
  const float* vq = (const float*)d_in[8];
  const float* gk = (const float*)d_in[9];
  const float* bk = (const float*)d_in[10];
  const float* mk = (const float*)d_in[11];
  const float* vk = (const float*)d_in[12];
  const float* gv = (const float*)d_in[13];
  const float* bv = (const float*)d_in[14];
  const float* mv = (const float*)d_in[15];
  const float* vv = (const float*)d_in[16];
  const float* gamma = (const float*)d_in[17];
  float* out = (float*)d_out;

  char* p = (char*)d_ws;
  float* x1u          = (float*)p;          p += (size_t)B_*C_*N_*4;   // 16 MB
  unsigned short* x1t = (unsigned short*)p; p += (size_t)B_*N_*C_*2;   // 8 MB
  unsigned short* x2t = (unsigned short*)p; p += (size_t)B_*N_*C_*2;   // 8 MB
  unsigned short* Qb  = (unsigned short*)p; p += (size_t)B_*N_*32*2;   // 1 MB
  unsigned short* Kb  = (unsigned short*)p; p += (size_t)B_*N_*32*2;   // 1 MB
  unsigned short* Vb  = (unsigned short*)p; p += (size_t)B_*C_*N_*2;   // 8 MB
  unsigned short* wqb = (unsigned short*)p; p += 32*256*2;
  unsigned short* wkb = (unsigned short*)p; p += 32*256*2;
  unsigned short* wvb = (unsigned short*)p; p += 256*256*2;
  float* biasq        = (float*)p;          p += 32*4;
  float* biask        = (float*)p;          p += 32*4;
  float* biasv        = (float*)p;          p += 256*4;

  fold_w_kernel<<<256, 256, 0, stream>>>(wq,wk,wv,gq,bq,mq,vq,gk,bk,mk,vk,gv,bv,mv,vv,
                                         wqb,wkb,wvb,biasq,biask,biasv);
  upsample_tr_kernel<<<dim3(64,4,4), 256, 0, stream>>>(x1, x1u, x1t);
  transpose_bf_kernel<<<dim3(64,4,4), 256, 0, stream>>>(x2, x2t);
  conv_mfma_kernel<32,false><<<dim3(64,4), 256, 0, stream>>>(x1t, wqb, biasq, Qb);
  conv_mfma_kernel<32,false><<<dim3(64,4), 256, 0, stream>>>(x2t, wkb, biask, Kb);
  conv_mfma_kernel<256,true><<<dim3(64,4), 256, 0, stream>>>(x2t, wvb, biasv, Vb);
  attn_kernel<<<dim3(128,4), 256, 0, stream>>>(Qb, Kb, Vb, x1u, gamma, out);
}

// Round 6
// 142.880 us; speedup vs baseline: 2.1877x; 1.0549x over previous
//
#include <hip/hip_runtime.h>

#define B_ 4
#define C_ 256
#define N_ 4096
#define LOG2E 1.4426950408889634f

typedef short short8 __attribute__((ext_vector_type(8)));
typedef short short4_ __attribute__((ext_vector_type(4)));
typedef float float4v __attribute__((ext_vector_type(4)));
typedef unsigned int uint2v __attribute__((ext_vector_type(2)));
typedef unsigned int u32;

__device__ inline unsigned short f2b(float x){
  unsigned u = __builtin_bit_cast(unsigned, x);
  u = u + 0x7FFFu + ((u >> 16) & 1u);
  return (unsigned short)(u >> 16);
}

__device__ inline u32 cvtpk(float lo, float hi){
  u32 r; asm("v_cvt_pk_bf16_f32 %0, %1, %2" : "=v"(r) : "v"(lo), "v"(hi)); return r;
}

__device__ inline void gload16(const void* g, void* l){
  __builtin_amdgcn_global_load_lds((const __attribute__((address_space(1))) u32*)g,
                                   (__attribute__((address_space(3))) u32*)l, 16, 0, 0);
}

// ---------------- fold BN into weights (log2e folded into Q path) ----------------
__global__ void fold_w_kernel(const float* __restrict__ wq, const float* __restrict__ wk,
    const float* __restrict__ wv,
    const float* gq, const float* bq, const float* mq, const float* vq,
    const float* gk, const float* bk, const float* mk, const float* vk,
    const float* gv, const float* bv, const float* mv, const float* vv,
    unsigned short* wqb, unsigned short* wkb, unsigned short* wvb,
    float* biasq, float* biask, float* biasv){
  int i = blockIdx.x*256 + threadIdx.x;   // 65536 threads
  int o = i >> 8;
  float sv = gv[o]*rsqrtf(vv[o]+1e-5f);
  wvb[i] = f2b(wv[i]*sv);
  if (i < 32*256){
    int oq = i >> 8;
    float sq = gq[oq]*rsqrtf(vq[oq]+1e-5f);
    wqb[i] = f2b(wq[i]*sq*LOG2E);
    float sk = gk[oq]*rsqrtf(vk[oq]+1e-5f);
    wkb[i] = f2b(wk[i]*sk);
  }
  if (i < 256) biasv[i] = bv[i] - mv[i]*(gv[i]*rsqrtf(vv[i]+1e-5f));
  if (i < 32){
    biasq[i] = (bq[i] - mq[i]*(gq[i]*rsqrtf(vq[i]+1e-5f)))*LOG2E;
    biask[i] = bk[i] - mk[i]*(gk[i]*rsqrtf(vk[i]+1e-5f));
  }
}

// ------- fused bilinear upsample + x1u(f32) store + Q conv (reads LDS tile) -------
// grid (64 y, 4 b), 256 threads. Block covers n = y*64 + x, all 256 c.
__global__ __launch_bounds__(256, 2)
void up_convq_kernel(const float* __restrict__ x1,
                     const unsigned short* __restrict__ wqb,
                     const float* __restrict__ biasq,
                     float* __restrict__ x1u,
                     unsigned short* __restrict__ Qb){
  __shared__ unsigned short xt[64*260];   // [x:64][c:256], stride 260 (8B-aligned rows)
  int b = blockIdx.y, y = blockIdx.x;
  int t = threadIdx.x;
  float fy = 0.5f*y - 0.25f;
  float y0f = floorf(fy); float wy = fy - y0f;
  int y0 = max(0,min(31,(int)y0f)), y1 = max(0,min(31,(int)y0f+1));
  int x = t & 63, cg = t >> 6;
  float fx = 0.5f*x - 0.25f;
  float x0f = floorf(fx); float wx = fx - x0f;
  int x0 = max(0,min(31,(int)x0f)), x1i = max(0,min(31,(int)x0f+1));
  #pragma unroll 8
  for (int i=0;i<64;i++){
    int c = cg + i*4;
    const float* s0 = x1 + ((size_t)(b*C_ + c)*32 + y0)*32;
    const float* s1 = x1 + ((size_t)(b*C_ + c)*32 + y1)*32;
    float v00=s0[x0], v01=s0[x1i], v10=s1[x0], v11=s1[x1i];
    float v0 = v00 + wx*(v01-v00), v1 = v10 + wx*(v11-v10);
    float val = v0 + wy*(v1-v0);
    x1u[(size_t)(b*C_ + c)*N_ + y*64 + x] = val;
    xt[x*260 + c] = f2b(val);
  }
  __syncthreads();
  int lane = t&63, w = t>>6, l15 = lane&15, g = lane>>4;
  const unsigned short* arow = xt + (w*16+l15)*260 + g*8;
  short8 a[8];
  #pragma unroll
  for (int kk=0;kk<8;kk++){
    short4_ lo = *(const short4_*)(arow + kk*32);
    short4_ hi = *(const short4_*)(arow + kk*32 + 4);
    short8 af;
    af[0]=lo[0];af[1]=lo[1];af[2]=lo[2];af[3]=lo[3];
    af[4]=hi[0];af[5]=hi[1];af[6]=hi[2];af[7]=hi[3];
    a[kk]=af;
  }
  #pragma unroll
  for (int ot=0; ot<2; ot++){
    int o = ot*16 + l15;
    const unsigned short* wrow = wqb + o*C_ + g*8;
    float4v acc = {0.f,0.f,0.f,0.f};
    #pragma unroll
    for (int kk=0;kk<8;kk++){
      short8 bf = *(const short8*)(wrow + kk*32);
      acc = __builtin_amdgcn_mfma_f32_16x16x32_bf16(a[kk], bf, acc, 0,0,0);
    }
    float bs = biasq[o];
    #pragma unroll
    for (int r=0;r<4;r++){
      float yv = acc[r] + bs;
      yv = yv >= 0.f ? yv : 0.1f*yv;
      int m = y*64 + w*16 + g*4 + r;
      Qb[(size_t)(b*N_+m)*32 + o] = f2b(yv);
    }
  }
}

// ------- fused x2 transpose-stage + K conv + V conv (shared A-frags) -------
// grid (64 nblk, 4 b), 256 threads.
__global__ __launch_bounds__(256, 2)
void x2_convkv_kernel(const float* __restrict__ x2,
                      const unsigned short* __restrict__ wkb,
                      const unsigned short* __restrict__ wvb,
                      const float* __restrict__ biask,
                      const float* __restrict__ biasv,
                      unsigned short* __restrict__ Kb,
                      unsigned short* __restrict__ Vb){
  __shared__ unsigned short xt[64*260];   // [n:64][c:256], stride 260
  int b = blockIdx.y, n0 = blockIdx.x*64;
  int t = threadIdx.x;
  int n = t & 63, cg = t >> 6;
  #pragma unroll 8
  for (int i=0;i<64;i++){
    int c = cg + i*4;
    float v = x2[(size_t)(b*C_ + c)*N_ + n0 + n];
    xt[n*260 + c] = f2b(v);
  }
  __syncthreads();
  int lane = t&63, w = t>>6, l15 = lane&15, g = lane>>4;
  const unsigned short* arow = xt + (w*16+l15)*260 + g*8;
  short8 a[8];
  #pragma unroll
  for (int kk=0;kk<8;kk++){
    short4_ lo = *(const short4_*)(arow + kk*32);
    short4_ hi = *(const short4_*)(arow + kk*32 + 4);
    short8 af;
    af[0]=lo[0];af[1]=lo[1];af[2]=lo[2];af[3]=lo[3];
    af[4]=hi[0];af[5]=hi[1];af[6]=hi[2];af[7]=hi[3];
    a[kk]=af;
  }
  // K conv (O=32) -> Kb [n][32]
  #pragma unroll
  for (int ot=0; ot<2; ot++){
    int o = ot*16 + l15;
    const unsigned short* wrow = wkb + o*C_ + g*8;
    float4v acc = {0.f,0.f,0.f,0.f};
    #pragma unroll
    for (int kk=0;kk<8;kk++){
      short8 bf = *(const short8*)(wrow + kk*32);
      acc = __builtin_amdgcn_mfma_f32_16x16x32_bf16(a[kk], bf, acc, 0,0,0);
    }
    float bs = biask[o];
    #pragma unroll
    for (int r=0;r<4;r++){
      float yv = acc[r] + bs;
      yv = yv >= 0.f ? yv : 0.1f*yv;
      int m = n0 + w*16 + g*4 + r;
      Kb[(size_t)(b*N_+m)*32 + o] = f2b(yv);
    }
  }
  // V conv (O=256) -> Vb [c][n]
  #pragma unroll
  for (int ot=0; ot<16; ot++){
    int o = ot*16 + l15;
    const unsigned short* wrow = wvb + (size_t)o*C_ + g*8;
    float4v acc = {0.f,0.f,0.f,0.f};
    #pragma unroll
    for (int kk=0;kk<8;kk++){
      short8 bf = *(const short8*)(wrow + kk*32);
      acc = __builtin_amdgcn_mfma_f32_16x16x32_bf16(a[kk], bf, acc, 0,0,0);
    }
    float bs = biasv[o];
    #pragma unroll
    for (int r=0;r<4;r++){
      float yv = acc[r] + bs;
      yv = yv >= 0.f ? yv : 0.1f*yv;
      int m = n0 + w*16 + g*4 + r;
      Vb[(size_t)(b*C_ + o)*N_ + m] = f2b(yv);
    }
  }
}

// ---------------- fused flash attention + gamma*out + x1u ----------------
// Grid 256 (XCD-swizzled: 64 m-blocks of 64 rows x 4 b), 512 threads (8 waves), 1 block/CU.
// Waves 0-3: softmax of 16-row tile w. All 8 waves: PV c-split (32 c each) + V staging.
__global__ __launch_bounds__(512, 2)
void attn_kernel(const unsigned short* __restrict__ Qb,
                 const unsigned short* __restrict__ Kb,
                 const unsigned short* __restrict__ Vb,
                 const float* __restrict__ x1u,
                 const float* __restrict__ gamma_p,
                 float* __restrict__ out){
  __shared__ __align__(16) char smem[74256];
  char* vbuf0 = smem;                         // 2 x 32768 V double-buffer
  char* vbuf1 = smem + 32768;
  char* pbase = smem + 65536;                 // 4 x 2048 P tiles
  float* scl  = (float*)(smem + 73728);       // 4 x 16 rescale factors
  float* lst  = (float*)(smem + 73984);       // 64 row sums
  int* flags  = (int*)(smem + 74240);         // 4 rescale flags

  int wg = blockIdx.y*64 + blockIdx.x;
  int id = (wg & 7)*32 + (wg >> 3);           // bijective XCD swizzle (256 = 8*32)
  int b = id >> 6, mblk = id & 63;
  int t = threadIdx.x, lane = t & 63, w = t >> 6;
  int l15 = lane & 15, g = lane >> 4;
  int swz = (l15 & 7) << 4;

  short8 qf;
  if (w < 4)
    qf = *(const short8*)(Qb + (size_t)(b*N_ + mblk*64 + w*16 + l15)*32 + g*8);

  float4v acc[4][2];   // [mt][ct]
  #pragma unroll
  for (int mt=0;mt<4;mt++)
    #pragma unroll
    for (int ct=0;ct<2;ct++) acc[mt][ct] = (float4v){0.f,0.f,0.f,0.f};
  float mrow = -1e30f, lrun = 0.f;
  const float4v zero4 = {0.f,0.f,0.f,0.f};

  // staging: 2048 16B chunks over 512 threads -> 4 each
  size_t goff[4]; int loff[4];
  #pragma unroll
  for (int j=0;j<4;j++){
    int i = j*512 + t;
    int c = i >> 3, jj = i & 7;
    loff[j] = i*16;
    goff[j] = (size_t)(b*C_ + c)*(N_*2) + ((size_t)((jj ^ (c & 7)) << 4));
  }
  const char* Vbyte = (const char*)Vb;

  auto stageV = [&](int tt, char* buf){
    const char* src = Vbyte + tt*128;
    #pragma unroll
    for (int j=0;j<4;j++) gload16(src + goff[j], buf + loff[j]);
  };
  auto loadK = [&](short8 (&kf)[4], int tt){
    const unsigned short* kp = Kb + (size_t)(b*N_ + tt*64 + l15)*32 + g*8;
    #pragma unroll
    for (int j=0;j<4;j++) kf[j] = *(const short8*)(kp + j*512);
  };

  auto body = [&](int tt, char* vb, short8 (&kfC)[4], short8 (&kfN)[4], int tn, char* nb){
    if (w < 4){
      // S^T = mfma(K, Q): lane l15 = m-row; n = j*16 + g*4 + r
      float4v s[4];
      #pragma unroll
      for (int j=0;j<4;j++)
        s[j] = __builtin_amdgcn_mfma_f32_16x16x32_bf16(kfC[j], qf, zero4, 0, 0, 0);
      float tmax = fmaxf(fmaxf(fmaxf(s[0][0],s[0][1]),fmaxf(s[0][2],s[0][3])),
                 fmaxf(fmaxf(fmaxf(s[1][0],s[1][1]),fmaxf(s[1][2],s[1][3])),
                 fmaxf(fmaxf(fmaxf(s[2][0],s[2][1]),fmaxf(s[2][2],s[2][3])),
                       fmaxf(fmaxf(s[3][0],s[3][1]),fmaxf(s[3][2],s[3][3])))));
      int trig = __any((tmax > mrow + 8.f) ? 1 : 0) ? 1 : 0;
      if (lane == 0) flags[w] = trig;
      if (trig){
        float tm = fmaxf(tmax, __shfl_xor(tmax, 16));
        tm = fmaxf(tm, __shfl_xor(tm, 32));
        float mnew = fmaxf(mrow, tm);
        float sc = exp2f(mrow - mnew);
        mrow = mnew; lrun *= sc;
        if (lane < 16) scl[w*16 + l15] = sc;
      }
      char* pw = pbase + w*2048 + l15*128;
      #pragma unroll
      for (int j=0;j<4;j++){
        float p0 = exp2f(s[j][0]-mrow), p1 = exp2f(s[j][1]-mrow);
        float p2 = exp2f(s[j][2]-mrow), p3 = exp2f(s[j][3]-mrow);
        lrun += (p0+p1)+(p2+p3);
        u32 lo = cvtpk(p0, p1);
        u32 hi = cvtpk(p2, p3);
        *(uint2v*)(pw + ((j*32 + g*8) ^ swz)) = (uint2v){lo, hi};
      }
    }
    __syncthreads();   // P/flags/scl visible; both V bufs idle from prior phases
    if (tn < 64){ stageV(tn, nb); if (w < 4) loadK(kfN, tn); }
    __builtin_amdgcn_sched_barrier(0);
    int f[4] = {flags[0], flags[1], flags[2], flags[3]};
    #pragma unroll
    for (int mt=0;mt<4;mt++){
      if (f[mt]){
        float4v sv = *(float4v*)((char*)scl + mt*64 + g*16);
        #pragma unroll
        for (int ct=0;ct<2;ct++){
          acc[mt][ct][0]*=sv[0]; acc[mt][ct][1]*=sv[1];
          acc[mt][ct][2]*=sv[2]; acc[mt][ct][3]*=sv[3];
        }
      }
    }
    // PV: acc[mt][ct] += P[mt] * V  (A = P rows m, B = V[k=n][col=c])
    #pragma unroll
    for (int kh=0; kh<2; kh++){
      int ko = (kh*64 + g*16) ^ swz;
      short8 pa0 = *(const short8*)(pbase +        l15*128 + ko);
      short8 pa1 = *(const short8*)(pbase + 2048 + l15*128 + ko);
      short8 pa2 = *(const short8*)(pbase + 4096 + l15*128 + ko);
      short8 pa3 = *(const short8*)(pbase + 6144 + l15*128 + ko);
      #pragma unroll
      for (int ct=0; ct<2; ct++){
        short8 vf = *(const short8*)(vb + (w*32 + ct*16 + l15)*128 + ko);
        acc[0][ct] = __builtin_amdgcn_mfma_f32_16x16x32_bf16(pa0, vf, acc[0][ct], 0, 0, 0);
        acc[1][ct] = __builtin_amdgcn_mfma_f32_16x16x32_bf16(pa1, vf, acc[1][ct], 0, 0, 0);
        acc[2][ct] = __builtin_amdgcn_mfma_f32_16x16x32_bf16(pa2, vf, acc[2][ct], 0, 0, 0);
        acc[3][ct] = __builtin_amdgcn_mfma_f32_16x16x32_bf16(pa3, vf, acc[3][ct], 0, 0, 0);
      }
    }
    __syncthreads();   // PV done; staged buf drained
  };

  short8 kfA[4], kfB[4];
  stageV(0, vbuf0);
  if (w < 4) loadK(kfA, 0);
  __syncthreads();
  for (int tt=0; tt<64; tt+=2){
    body(tt,   vbuf0, kfA, kfB, tt+1, vbuf1);
    body(tt+1, vbuf1, kfB, kfA, tt+2, vbuf0);
  }

  // epilogue
  if (w < 4){
    lrun += __shfl_xor(lrun, 16);
    lrun += __shfl_xor(lrun, 32);
    if (lane < 16) lst[w*16 + l15] = lrun;
  }
  __syncthreads();
  float4v lv[4];
  #pragma unroll
  for (int mt=0;mt<4;mt++) lv[mt] = *(float4v*)((char*)lst + mt*64 + g*16);
  float gm = gamma_p[0];
  float* ow = (float*)smem + w*2112;   // 64 x 33 f32 per wave (overlays v/p bufs)
  #pragma unroll
  for (int mt=0;mt<4;mt++){
    #pragma unroll
    for (int ct=0;ct<2;ct++){
      #pragma unroll
      for (int r=0;r<4;r++)
        ow[(mt*16 + g*4 + r)*33 + ct*16 + l15] = acc[mt][ct][r] / lv[mt][r];
    }
  }
  __syncthreads();
  const float* xr = x1u + (size_t)(b*C_ + w*32)*N_ + mblk*64;
  float* orow = out + (size_t)(b*C_ + w*32)*N_ + mblk*64;
  #pragma unroll 4
  for (int cl=0; cl<32; cl++){
    float v = ow[lane*33 + cl];
    orow[(size_t)cl*N_ + lane] = gm*v + xr[(size_t)cl*N_ + lane];
  }
}

extern "C" void kernel_launch(void* const* d_in, const int* in_sizes, int n_in,
                              void* d_out, int out_size, void* d_ws, size_t ws_size,
                              hipStream_t stream){
  (void)in_sizes; (void)n_in; (void)out_size; (void)ws_size;
  const float* x1 = (const float*)d_in[0];
  const float* x2 = (const float*)d_in[1];
  const float* wq = (const float*)d_in[2];
  const float* wk = (const float*)d_in[3];
  const float* wv = (const float*)d_in[4];
  const float* gq = (const float*)d_in[5];
  const float* bq = (const float*)d_in[6];
  const float* mq = (const float*)d_in[7];
  const float* vq = (const float*)d_in[8];
  const float* gk = (const float*)d_in[9];
  const float* bk = (const float*)d_in[10];
  const float* mk = (const float*)d_in[11];
  const float* vk = (const float*)d_in[12];
  const float* gv = (const float*)d_in[13];
  const float* bv = (const float*)d_in[14];
  const float* mv = (const float*)d_in[15];
  const float* vv = (const float*)d_in[16];
  const float* gamma = (const float*)d_in[17];
  float* out = (float*)d_out;

  char* p = (char*)d_ws;
  float* x1u          = (float*)p;          p += (size_t)B_*C_*N_*4;   // 16 MB
  unsigned short* Qb  = (unsigned short*)p; p += (size_t)B_*N_*32*2;   // 1 MB
  unsigned short* Kb  = (unsigned short*)p; p += (size_t)B_*N_*32*2;   // 1 MB
  unsigned short* Vb  = (unsigned short*)p; p += (size_t)B_*C_*N_*2;   // 8 MB
  unsigned short* wqb = (unsigned short*)p; p += 32*256*2;
  unsigned short* wkb = (unsigned short*)p; p += 32*256*2;
  unsigned short* wvb = (unsigned short*)p; p += 256*256*2;
  float* biasq        = (float*)p;          p += 32*4;
  float* biask        = (float*)p;          p += 32*4;
  float* biasv        = (float*)p;          p += 256*4;

  fold_w_kernel<<<256, 256, 0, stream>>>(wq,wk,wv,gq,bq,mq,vq,gk,bk,mk,vk,gv,bv,mv,vv,
                                         wqb,wkb,wvb,biasq,biask,biasv);
  up_convq_kernel<<<dim3(64,4), 256, 0, stream>>>(x1, wqb, biasq, x1u, Qb);
  x2_convkv_kernel<<<dim3(64,4), 256, 0, stream>>>(x2, wkb, wvb, biask, biasv, Kb, Vb);
  attn_kernel<<<dim3(64,4), 512, 0, stream>>>(Qb, Kb, Vb, x1u, gamma, out);
}